// Round 2
// baseline (593.076 us; speedup 1.0000x reference)
//
#include <hip/hip_runtime.h>
#include <math.h>

// Problem constants: B=4, S=4096, H=32, D=64, STEP=32, N_STEPS=128
#define BB 4
#define SS 4096
#define HH 32
#define DD 64
#define NSTEPS 128

#define SUBC 64                  // positions per sub-chunk (one wave each)
#define SC_PER_BH (SS / SUBC)    // 64 sub-chunks per (b,h)
#define WAVES 4                  // waves per block (256 threads)

// v + dpp_perm(v); ctrl must be a literal
#define DPP_ADD(v, ctrl) \
    ((v) + __int_as_float(__builtin_amdgcn_update_dpp(0, __float_as_int(v), (ctrl), 0xF, 0xF, true)))

// Full 64-lane sum, result uniform (lands in SGPR via readlane).
// xor1/2 = quad_perm, xor4 = row_half_mirror, xor8 = row_mirror (VALU DPP);
// xor16 = ds_swizzle 0x401F; cross-32 = 2x v_readlane + add.
__device__ __forceinline__ float wave_allsum(float v) {
    v = DPP_ADD(v, 0xB1);   // quad_perm [1,0,3,2]  : xor 1
    v = DPP_ADD(v, 0x4E);   // quad_perm [2,3,0,1]  : xor 2
    v = DPP_ADD(v, 0x141);  // row_half_mirror      : xor 4
    v = DPP_ADD(v, 0x140);  // row_mirror           : xor 8
    v = v + __int_as_float(__builtin_amdgcn_ds_swizzle(__float_as_int(v), 0x401F)); // xor 16
    float a = __int_as_float(__builtin_amdgcn_readlane(__float_as_int(v), 0));
    float b = __int_as_float(__builtin_amdgcn_readlane(__float_as_int(v), 32));
    return a + b;
}

// Phase 1: per-sub-chunk kn sums + per-position reciprocal norms for k and q.
// Grid (SC_PER_BH/WAVES, H, B), block 256; lane = dim d.
__global__ __launch_bounds__(256) void phase1(
    const float* __restrict__ q, const float* __restrict__ k,
    float* __restrict__ sums, float* __restrict__ krs_out, float* __restrict__ qrs_out) {
    const int lane = threadIdx.x & 63;
    const int wave = threadIdx.x >> 6;
    const int sc = blockIdx.x * WAVES + wave;
    const int h = blockIdx.y;
    const int b = blockIdx.z;
    const int p0 = sc * SUBC;
    size_t base = ((size_t)b * SS + p0) * (HH * DD) + (size_t)h * DD + lane;

    float acc = 0.f;
    float krs_keep = 0.f, qrs_keep = 0.f;
#pragma unroll 4
    for (int i = 0; i < SUBC; ++i) {
        size_t idx = base + (size_t)i * (HH * DD);
        float kv = k[idx];
        float qv = q[idx];
        float kr = fmaxf(kv, 0.f);
        float qr = fmaxf(qv, 0.f);
        float kss = wave_allsum(kr * kr);
        float qss = wave_allsum(qr * qr);
        float krs = __builtin_amdgcn_rcpf(sqrtf(kss) + 1e-6f);
        float qrs = __builtin_amdgcn_rcpf((sqrtf(qss) + 1e-6f) * 32.0f); // fold /STEP
        acc += kr * krs;
        krs_keep = (lane == i) ? krs : krs_keep;
        qrs_keep = (lane == i) ? qrs : qrs_keep;
    }
    sums[(((size_t)b * HH + h) * SC_PER_BH + sc) * DD + lane] = acc;
    size_t pbase = ((size_t)b * HH + h) * SS + (size_t)p0;
    krs_out[pbase + lane] = krs_keep;
    qrs_out[pbase + lane] = qrs_keep;
}

// Phase 2: exclusive chunk offset, then 64-position walk with ONE reduction/position.
__global__ __launch_bounds__(256) void phase2(
    const float* __restrict__ q, const float* __restrict__ k,
    const float* __restrict__ cosst, const float* __restrict__ sinst,
    const float* __restrict__ sums,
    const float* __restrict__ krs_in, const float* __restrict__ qrs_in,
    float* __restrict__ outq, float* __restrict__ outk) {
    __shared__ float4 tbl[NSTEPS];  // (c0, c1-c0, s0, s1-s0) per step — 2 KB
    {
        int t = threadIdx.x;
        if (t < NSTEPS) {
            int t1 = (t + 1 < NSTEPS) ? t + 1 : t;
            float c0 = cosst[(size_t)t * DD];
            float s0 = sinst[(size_t)t * DD];
            float c1 = cosst[(size_t)t1 * DD];
            float s1 = sinst[(size_t)t1 * DD];
            tbl[t] = make_float4(c0, c1 - c0, s0, s1 - s0);
        }
    }
    __syncthreads();

    const int lane = threadIdx.x & 63;
    const int wave = threadIdx.x >> 6;
    const int sc = blockIdx.x * WAVES + wave;
    const int h = blockIdx.y;
    const int b = blockIdx.z;

    // exclusive prefix over earlier sub-chunks (2 MiB array, L2-hot)
    const float* srow = sums + (((size_t)b * HH + h) * SC_PER_BH) * DD + lane;
    float off = 0.f;
    for (int cc = 0; cc < sc; ++cc) off += srow[(size_t)cc * DD];

    const int p0 = sc * SUBC;
    size_t pbase = ((size_t)b * HH + h) * SS + (size_t)p0;
    float krs_vec = krs_in[pbase + lane];  // lane i holds 1/(|kr|+eps) of position p0+i
    float qrs_vec = qrs_in[pbase + lane];  // lane i holds 1/(32(|qr|+eps))

    const float sgn = (lane < 32) ? -1.f : 1.f;
    const int xaddr = (lane ^ 32) << 2;    // bpermute byte address for rotate_half

    size_t base = ((size_t)b * SS + p0) * (HH * DD) + (size_t)h * DD + lane;
    float cumk = off;
#pragma unroll 4
    for (int i = 0; i < SUBC; ++i) {
        size_t idx = base + (size_t)i * (HH * DD);
        float kv = k[idx];
        float qv = q[idx];

        float krs = __int_as_float(__builtin_amdgcn_readlane(__float_as_int(krs_vec), i));
        float qrs = __int_as_float(__builtin_amdgcn_readlane(__float_as_int(qrs_vec), i));

        float kn = fmaxf(kv, 0.f) * krs;
        cumk += kn;
        float qn = fmaxf(qv, 0.f) * qrs;   // includes 1/STEP

        float pos = wave_allsum(qn * cumk);          // = dot/32, uniform
        pos = fminf(fmaxf(pos, 0.f), (float)(NSTEPS - 1));
        float pf = floorf(pos);
        int pfi = (int)pf;
        float frac = pos - pf;

        float4 tv = tbl[pfi];                        // broadcast ds_read_b128
        float cosp = fmaf(frac, tv.y, tv.x);
        float sinp = fmaf(frac, tv.w, tv.z);
        float rsin = sinp * sgn;

        float rq = __int_as_float(__builtin_amdgcn_ds_bpermute(xaddr, __float_as_int(qv)));
        float rk = __int_as_float(__builtin_amdgcn_ds_bpermute(xaddr, __float_as_int(kv)));

        outq[idx] = fmaf(qv, cosp, rq * rsin);
        outk[idx] = fmaf(kv, cosp, rk * rsin);
    }
}

extern "C" void kernel_launch(void* const* d_in, const int* in_sizes, int n_in,
                              void* d_out, int out_size, void* d_ws, size_t ws_size,
                              hipStream_t stream) {
    const float* q = (const float*)d_in[0];
    const float* k = (const float*)d_in[1];
    // d_in[2] = v (unused)
    const float* cosst = (const float*)d_in[3];
    const float* sinst = (const float*)d_in[4];
    // d_in[5] = offset (unused)

    float* outq = (float*)d_out;
    float* outk = outq + (size_t)BB * SS * HH * DD;

    float* sums = (float*)d_ws;                                   // 2 MiB
    float* krs = sums + (size_t)BB * HH * SC_PER_BH * DD;         // 2 MiB
    float* qrs = krs + (size_t)BB * HH * SS;                      // 2 MiB

    dim3 grid(SC_PER_BH / WAVES, HH, BB);  // (16, 32, 4)
    phase1<<<grid, 256, 0, stream>>>(q, k, sums, krs, qrs);
    phase2<<<grid, 256, 0, stream>>>(q, k, cosst, sinst, sums, krs, qrs, outq, outk);
}